// Round 17
// baseline (81.681 us; speedup 1.0000x reference)
//
#include <hip/hip_runtime.h>
#include <math.h>

// Problem constants
#define B_   128
#define I_   2048
#define F_   8
#define J_   16
#define D_   16
#define JD   256
#define IT   16
#define NIT  (I_/IT)       // 128
#define BT2  32            // pass0 b-tile (proven r14 config)
#define NBG2 (B_/BT2)      // 4
#define BT3  64            // pass1/2 b-tile (this round's single variable)
#define NBG3 (B_/BT3)      // 2
#define SROW 257           // padded slds row stride (f32)
#define CLS3 65            // padded cl b-stride for BT3 (f32, odd)

typedef _Float16 f16;
typedef _Float16 f16x8 __attribute__((ext_vector_type(8)));
typedef float    f32x4 __attribute__((ext_vector_type(4)));

#if defined(__has_builtin)
#  if __has_builtin(__builtin_amdgcn_permlane32_swap)
#    define HAVE_PLS32 1
#  endif
#endif

// 16-lane DPP sum — pure VALU (reduce kernel)
template <int CTRL>
__device__ __forceinline__ float dpp_add(float v) {
    int t = __builtin_amdgcn_update_dpp(0, __float_as_int(v), CTRL, 0xF, 0xF, true);
    return v + __int_as_float(t);
}
__device__ __forceinline__ float row_sum16(float v) {
    v = dpp_add<0x128>(v);
    v = dpp_add<0x124>(v);
    v = dpp_add<0x122>(v);
    v = dpp_add<0x121>(v);
    return v;
}

// quarter-sum folds for MFMA C-layout (proven rounds 5-16)
__device__ __forceinline__ float fold16(float p) {
    return p + __int_as_float(__builtin_amdgcn_ds_swizzle(__float_as_int(p), 0x401F));
}
__device__ __forceinline__ float fold32(float p) {
#ifdef HAVE_PLS32
    auto r = __builtin_amdgcn_permlane32_swap(__float_as_int(p), __float_as_int(p),
                                              false, false);
    return __int_as_float(r[0]) + __int_as_float(r[1]);
#else
    return p + __shfl_xor(p, 32);
#endif
}

__device__ __forceinline__ f16x8 cvt8(float4 a0, float4 a1) {
    f16x8 h = {(f16)a0.x, (f16)a0.y, (f16)a0.z, (f16)a0.w,
               (f16)a1.x, (f16)a1.y, (f16)a1.z, (f16)a1.w};
    return h;
}

// ---------------------------------------------------------------------------
// Pass 0 — verbatim round 14/16 (proven). BT2=32, 512 threads, fused cvt.
// ---------------------------------------------------------------------------
__global__ __launch_bounds__(512, 4) void caps_pass0(
    const float* __restrict__ Wf,   // [J][I][D][F] f32
    const float* __restrict__ xf,   // [B][I][F] f32
    f16* __restrict__ Wt,           // [J][I][D][F] f16 (out)
    f16* __restrict__ xt,           // [B][I][F] f16 (out)
    f16* __restrict__ sp)           // [NIT][B][JD] f16
{
    const int it = blockIdx.x, bg = blockIdx.y;
    const int i0 = it * IT, b0 = bg * BT2;
    const int t = threadIdx.x;
    const int w = t >> 6, l = t & 63;        // w in 0..7 -> j = w*2 + jj
    const int lb = l & 15, lq = l >> 4;

    __shared__ f16   xlds[IT][BT2][F_];      // 8 KB
    __shared__ float slds[BT2 * SROW];       // 32.9 KB

    {
        const int b = t >> 4, i = t & 15;
        const size_t off = ((size_t)(b0 + b) * I_ + i0 + i) * F_;
        const float4* src = reinterpret_cast<const float4*>(xf + off);
        f16x8 h = cvt8(src[0], src[1]);
        *reinterpret_cast<f16x8*>(xt + off) = h;
        *reinterpret_cast<f16x8*>(&xlds[i][b][0]) = h;
    }
    __syncthreads();

    const f32x4 zero = {0.f, 0.f, 0.f, 0.f};
    f32x4 sacc[2][2] = {{zero, zero}, {zero, zero}};

    #pragma unroll
    for (int m = 0; m < 4; ++m) {
        const int i = m * 4 + lq;
        f16x8 xv0 = *reinterpret_cast<const f16x8*>(&xlds[i][lb][0]);
        f16x8 xv1 = *reinterpret_cast<const f16x8*>(&xlds[i][16 + lb][0]);
        #pragma unroll
        for (int jj = 0; jj < 2; ++jj) {
            const size_t off =
                (((size_t)(w * 2 + jj) * I_ + i0 + i) * D_ + lb) * F_;
            const float4* sw = reinterpret_cast<const float4*>(Wf + off);
            f16x8 af = cvt8(sw[0], sw[1]);
            if (bg == 0) *reinterpret_cast<f16x8*>(Wt + off) = af;
            sacc[jj][0] = __builtin_amdgcn_mfma_f32_16x16x32_f16(
                af, xv0, sacc[jj][0], 0, 0, 0);
            sacc[jj][1] = __builtin_amdgcn_mfma_f32_16x16x32_f16(
                af, xv1, sacc[jj][1], 0, 0, 0);
        }
    }

    #pragma unroll
    for (int jj = 0; jj < 2; ++jj) {
        const int j = w * 2 + jj;
        #pragma unroll
        for (int bh = 0; bh < 2; ++bh) {
            f32x4 sv = sacc[jj][bh] * 0.0625f;
            #pragma unroll
            for (int r = 0; r < 4; ++r)
                slds[(bh * 16 + lb) * SROW + j * D_ + lq * 4 + r] = sv[r];
        }
    }
    __syncthreads();
    {
        const int b = t >> 4, seg = t & 15;
        float o[16];
        #pragma unroll
        for (int k = 0; k < 16; ++k)
            o[k] = slds[b * SROW + seg * 16 + k];
        f16x8 o0 = {(f16)o[0], (f16)o[1], (f16)o[2],  (f16)o[3],
                    (f16)o[4], (f16)o[5], (f16)o[6],  (f16)o[7]};
        f16x8 o1 = {(f16)o[8], (f16)o[9], (f16)o[10], (f16)o[11],
                    (f16)o[12], (f16)o[13], (f16)o[14], (f16)o[15]};
        f16* dst = sp + ((size_t)it * B_ + b0 + b) * JD + seg * 16;
        *reinterpret_cast<f16x8*>(dst) = o0;
        *reinterpret_cast<f16x8*>(dst + 8) = o1;
    }
}

// ---------------------------------------------------------------------------
// Pass 1/2 — BT3=64, 512 threads (8 waves, 2 j per wave, 4 b-halves).
// r13's validated lever applied once more: each af load now feeds 4 b-half
// MFMAs (phase-A W L2-traffic 33.6 -> 16.8 MB/pass). Grid (128,2) = 256
// blocks = 1 block/CU; same-it pairs are 128 apart -> same XCD L2.
// LDS 82.6 KB/WG (>64 KB is supported on gfx950 — HK 8-phase uses 128 KB).
// NOTE (r15): no conditional register capture of af — cndmask trap.
// ---------------------------------------------------------------------------
__global__ __launch_bounds__(512, 2) void caps_pass1(
    const f16* __restrict__ Wt,     // [J][I][D][F]
    const f16* __restrict__ xt,     // [B][I][F]
    const float* __restrict__ vsum, // [B][JD]
    f16* __restrict__ sp)           // [NIT][B][JD]
{
    const int it = blockIdx.x, bg = blockIdx.y;
    const int i0 = it * IT, b0 = bg * BT3;
    const int t = threadIdx.x;
    const int w = t >> 6, l = t & 63;        // w in 0..7 -> j = w*2 + jj
    const int lb = l & 15, lq = l >> 4;

    __shared__ f16 xlds[IT][BT3][F_];       // 16 KB
    __shared__ union {
        float cl[J_ * IT * CLS3];           // 66.6 KB softmax coeffs
        float slds[BT3 * SROW];             // 65.8 KB epilogue transpose
    } sh;

    // stage x~ tile: thread (b = t>>3, i = (t&7)*2 + k)
    {
        const int b = t >> 3;
        #pragma unroll
        for (int k = 0; k < 2; ++k) {
            const int i = (t & 7) * 2 + k;
            f16x8 v = *reinterpret_cast<const f16x8*>(
                xt + ((size_t)(b0 + b) * I_ + i0 + i) * F_);
            *reinterpret_cast<f16x8*>(&xlds[i][b][0]) = v;
        }
    }

    // per-j W~ base pointers
    const f16* wp[2];
    #pragma unroll
    for (int jj = 0; jj < 2; ++jj)
        wp[jj] = Wt + (((size_t)(w * 2 + jj) * I_ + i0) * D_ + lb) * F_;

    const f32x4 zero = {0.f, 0.f, 0.f, 0.f};

    // v fragments: vr[jj][bh] = vsum[b0+bh*16+lb][j][lq*4 .. +3]
    float4 vr[2][4];
    #pragma unroll
    for (int jj = 0; jj < 2; ++jj)
        #pragma unroll
        for (int bh = 0; bh < 4; ++bh)
            vr[jj][bh] = *reinterpret_cast<const float4*>(
                vsum + (size_t)(b0 + bh * 16 + lb) * JD +
                (w * 2 + jj) * D_ + lq * 4);
    __syncthreads();

    // ---- Phase A: logits (one af load feeds 4 b-half MFMAs) ----
    #pragma unroll 2
    for (int il = 0; il < IT; ++il) {
        f16x8 bf[4];
        #pragma unroll
        for (int bh = 0; bh < 4; ++bh) bf[bh] = (f16x8){0, 0, 0, 0, 0, 0, 0, 0};
        if (l < 16) {
            #pragma unroll
            for (int bh = 0; bh < 4; ++bh)
                bf[bh] = *reinterpret_cast<const f16x8*>(
                    &xlds[il][bh * 16 + lb][0]);
        }
        #pragma unroll
        for (int jj = 0; jj < 2; ++jj) {
            f16x8 af = *reinterpret_cast<const f16x8*>(wp[jj] + il * (D_ * F_));
            const int j = w * 2 + jj;
            #pragma unroll
            for (int bh = 0; bh < 4; ++bh) {
                f32x4 u = __builtin_amdgcn_mfma_f32_16x16x32_f16(
                    af, bf[bh], zero, 0, 0, 0);
                float p = u[0] * vr[jj][bh].x + u[1] * vr[jj][bh].y +
                          u[2] * vr[jj][bh].z + u[3] * vr[jj][bh].w;
                p = fold32(fold16(p));
                if (l < 16) sh.cl[(j * IT + il) * CLS3 + bh * 16 + lb] = p;
            }
        }
    }
    __syncthreads();

    // ---- softmax over j: 1024 (i,b) items, 2 per thread ----
    #pragma unroll
    for (int h = 0; h < 2; ++h) {
        const int item = h * 512 + t;
        const int i = item >> 6, b = item & 63;
        float e[J_];
        float mx = -1e30f;
        #pragma unroll
        for (int j = 0; j < J_; ++j) {
            e[j] = sh.cl[(j * IT + i) * CLS3 + b];
            mx = fmaxf(mx, e[j]);
        }
        float ssum = 0.f;
        #pragma unroll
        for (int j = 0; j < J_; ++j) { e[j] = __expf(e[j] - mx); ssum += e[j]; }
        const float inv = 1.f / ssum;
        #pragma unroll
        for (int j = 0; j < J_; ++j) sh.cl[(j * IT + i) * CLS3 + b] = e[j] * inv;
    }
    __syncthreads();

    // ---- Phase C: s-GEMM, K=(i16,f8)=128 -> 4 MFMAs per (j,bh) ----
    f32x4 sacc[2][4] = {{zero, zero, zero, zero}, {zero, zero, zero, zero}};
    #pragma unroll
    for (int m = 0; m < 4; ++m) {
        const int i = m * 4 + lq;
        f16x8 xv[4];
        #pragma unroll
        for (int bh = 0; bh < 4; ++bh)
            xv[bh] = *reinterpret_cast<const f16x8*>(&xlds[i][bh * 16 + lb][0]);
        #pragma unroll
        for (int jj = 0; jj < 2; ++jj) {
            const int j = w * 2 + jj;
            f16x8 af = *reinterpret_cast<const f16x8*>(wp[jj] + i * (D_ * F_));
            #pragma unroll
            for (int bh = 0; bh < 4; ++bh) {
                const f16 c = (f16)sh.cl[(j * IT + i) * CLS3 + bh * 16 + lb];
                f16x8 bfv = xv[bh] * c;    // v_pk_mul_f16
                sacc[jj][bh] = __builtin_amdgcn_mfma_f32_16x16x32_f16(
                    af, bfv, sacc[jj][bh], 0, 0, 0);
            }
        }
    }
    __syncthreads();   // slds aliases cl: phase-C cl reads must finish

    // ---- epilogue: LDS transpose -> coalesced f16 store ----
    #pragma unroll
    for (int jj = 0; jj < 2; ++jj) {
        const int j = w * 2 + jj;
        #pragma unroll
        for (int bh = 0; bh < 4; ++bh)
            #pragma unroll
            for (int r = 0; r < 4; ++r)
                sh.slds[(bh * 16 + lb) * SROW + j * D_ + lq * 4 + r] =
                    sacc[jj][bh][r];
    }
    __syncthreads();
    {
        const int b = t >> 3, seg = t & 7;   // 64 b x 8 segments of 32 jd
        float o[32];
        #pragma unroll
        for (int k = 0; k < 32; ++k)
            o[k] = sh.slds[b * SROW + seg * 32 + k];
        f16* dst = sp + ((size_t)it * B_ + b0 + b) * JD + seg * 32;
        #pragma unroll
        for (int q = 0; q < 4; ++q) {
            f16x8 hh = {(f16)o[q * 8 + 0], (f16)o[q * 8 + 1], (f16)o[q * 8 + 2],
                        (f16)o[q * 8 + 3], (f16)o[q * 8 + 4], (f16)o[q * 8 + 5],
                        (f16)o[q * 8 + 6], (f16)o[q * 8 + 7]};
            *reinterpret_cast<f16x8*>(dst + q * 8) = hh;
        }
    }
}

// ---------------------------------------------------------------------------
// Reduce over i-tiles + squash (verbatim rounds 7-16). Grid (B, 2), 512 thr.
// MODE 0: vA = squash(s); MODE 1: vB = vA + squash(s); MODE 2: out = squash(s)
// ---------------------------------------------------------------------------
template <int MODE>
__global__ __launch_bounds__(512) void caps_reduce(
    const f16* __restrict__ sp,    // [NIT][B][JD] f16
    const float* __restrict__ vA,  // [B][JD] (MODE==1)
    float* __restrict__ vout)      // [B][JD]
{
    const int b = blockIdx.x, jh = blockIdx.y;
    const int t = threadIdx.x;
    const int g = t >> 4, c8 = t & 15;
    constexpr int ITS = NIT / 32;  // 4

    float acc[8] = {0.f, 0.f, 0.f, 0.f, 0.f, 0.f, 0.f, 0.f};
    const f16* base = sp + ((size_t)(g * ITS) * B_ + b) * JD + jh * 128 + c8 * 8;
    #pragma unroll
    for (int k = 0; k < ITS; ++k) {
        f16x8 v = *reinterpret_cast<const f16x8*>(base + (size_t)k * B_ * JD);
        #pragma unroll
        for (int e = 0; e < 8; ++e) acc[e] += (float)v[e];
    }

    __shared__ float lds[32][128];
    #pragma unroll
    for (int e = 0; e < 8; ++e) lds[g][c8 * 8 + e] = acc[e];
    __syncthreads();

    if (t < 128) {
        float a = 0.f;
        #pragma unroll
        for (int gg = 0; gg < 32; ++gg) a += lds[gg][t];
        const float sq = row_sum16(a * a);
        const float scale = sq / (1.f + sq) * rsqrtf(sq + 1e-7f);
        float v = scale * a;
        const int jd = jh * 128 + t;
        if (MODE == 1) v += vA[(size_t)b * JD + jd];
        vout[(size_t)b * JD + jd] = v;
    }
}

extern "C" void kernel_launch(void* const* d_in, const int* in_sizes, int n_in,
                              void* d_out, int out_size, void* d_ws,
                              size_t ws_size, hipStream_t stream) {
    const float* x = (const float*)d_in[0];   // [128, 2048, 8]
    const float* W = (const float*)d_in[1];   // [16, 2048, 16, 8]
    float* out = (float*)d_out;               // [128, 16, 16]

    const size_t NW = (size_t)J_ * I_ * D_ * F_;   // 4,194,304
    const size_t NX = (size_t)B_ * I_ * F_;        // 2,097,152
    const size_t NSP = (size_t)NIT * B_ * JD;      // 4,194,304

    f16* Wt = (f16*)d_ws;
    f16* xt = Wt + NW;
    f16* sp = xt + NX;
    float* vA = (float*)(sp + NSP);
    float* vB = vA + (size_t)B_ * JD;

    dim3 grid0(NIT, NBG2), blk0(512);
    dim3 grid1(NIT, NBG3), blk1(512);
    dim3 rgrid(B_, 2), rblk(512);

    // r=0 (+ fused cvt): uniform c -> sp -> vA = v0
    caps_pass0<<<grid0, blk0, 0, stream>>>(W, x, Wt, xt, sp);
    caps_reduce<0><<<rgrid, rblk, 0, stream>>>(sp, nullptr, vA);
    // r=1: logits = vA.u_hat -> sp -> vB = vA + v1
    caps_pass1<<<grid1, blk1, 0, stream>>>(Wt, xt, vA, sp);
    caps_reduce<1><<<rgrid, rblk, 0, stream>>>(sp, vA, vB);
    // r=2: logits = vB.u_hat -> sp -> out
    caps_pass1<<<grid1, blk1, 0, stream>>>(Wt, xt, vB, sp);
    caps_reduce<2><<<rgrid, rblk, 0, stream>>>(sp, nullptr, out);
}

// Round 18
// 68.424 us; speedup vs baseline: 1.1938x; 1.1938x over previous
//
#include <hip/hip_runtime.h>
#include <math.h>

// Problem constants
#define B_   128
#define I_   2048
#define F_   8
#define J_   16
#define D_   16
#define JD   256
#define IT   16
#define NIT  (I_/IT)       // 128
#define BT2  32            // b per block (both passes)
#define NBG2 (B_/BT2)      // 4
#define SROW 257           // padded slds row stride (f32)
#define CLS  33            // padded cl b-stride (f32, odd)

typedef _Float16 f16;
typedef _Float16 f16x8 __attribute__((ext_vector_type(8)));
typedef float    f32x4 __attribute__((ext_vector_type(4)));

#if defined(__has_builtin)
#  if __has_builtin(__builtin_amdgcn_permlane32_swap)
#    define HAVE_PLS32 1
#  endif
#endif

// 16-lane DPP sum — pure VALU (reduce kernel)
template <int CTRL>
__device__ __forceinline__ float dpp_add(float v) {
    int t = __builtin_amdgcn_update_dpp(0, __float_as_int(v), CTRL, 0xF, 0xF, true);
    return v + __int_as_float(t);
}
__device__ __forceinline__ float row_sum16(float v) {
    v = dpp_add<0x128>(v);
    v = dpp_add<0x124>(v);
    v = dpp_add<0x122>(v);
    v = dpp_add<0x121>(v);
    return v;
}

// quarter-sum folds for MFMA C-layout (proven rounds 5-16)
__device__ __forceinline__ float fold16(float p) {
    return p + __int_as_float(__builtin_amdgcn_ds_swizzle(__float_as_int(p), 0x401F));
}
__device__ __forceinline__ float fold32(float p) {
#ifdef HAVE_PLS32
    auto r = __builtin_amdgcn_permlane32_swap(__float_as_int(p), __float_as_int(p),
                                              false, false);
    return __int_as_float(r[0]) + __int_as_float(r[1]);
#else
    return p + __shfl_xor(p, 32);
#endif
}

__device__ __forceinline__ f16x8 cvt8(float4 a0, float4 a1) {
    f16x8 h = {(f16)a0.x, (f16)a0.y, (f16)a0.z, (f16)a0.w,
               (f16)a1.x, (f16)a1.y, (f16)a1.z, (f16)a1.w};
    return h;
}

// ---------------------------------------------------------------------------
// Pass 0 — BT2=32, 512 threads (8 waves, 2 j per wave, 2 b-halves), fused
// f32->f16 conversion. One f32 W load per (m,jj), converted once, reused for
// both b-half MFMAs; bg==0 writes Wt.
// ---------------------------------------------------------------------------
__global__ __launch_bounds__(512, 4) void caps_pass0(
    const float* __restrict__ Wf,   // [J][I][D][F] f32
    const float* __restrict__ xf,   // [B][I][F] f32
    f16* __restrict__ Wt,           // [J][I][D][F] f16 (out)
    f16* __restrict__ xt,           // [B][I][F] f16 (out)
    f16* __restrict__ sp)           // [NIT][B][JD] f16
{
    const int it = blockIdx.x, bg = blockIdx.y;
    const int i0 = it * IT, b0 = bg * BT2;
    const int t = threadIdx.x;
    const int w = t >> 6, l = t & 63;        // w in 0..7 -> j = w*2 + jj
    const int lb = l & 15, lq = l >> 4;

    __shared__ f16   xlds[IT][BT2][F_];      // 8 KB
    __shared__ float slds[BT2 * SROW];       // 32.9 KB

    {
        const int b = t >> 4, i = t & 15;
        const size_t off = ((size_t)(b0 + b) * I_ + i0 + i) * F_;
        const float4* src = reinterpret_cast<const float4*>(xf + off);
        f16x8 h = cvt8(src[0], src[1]);
        *reinterpret_cast<f16x8*>(xt + off) = h;
        *reinterpret_cast<f16x8*>(&xlds[i][b][0]) = h;
    }
    __syncthreads();

    const f32x4 zero = {0.f, 0.f, 0.f, 0.f};
    f32x4 sacc[2][2] = {{zero, zero}, {zero, zero}};

    #pragma unroll
    for (int m = 0; m < 4; ++m) {
        const int i = m * 4 + lq;
        f16x8 xv0 = *reinterpret_cast<const f16x8*>(&xlds[i][lb][0]);
        f16x8 xv1 = *reinterpret_cast<const f16x8*>(&xlds[i][16 + lb][0]);
        #pragma unroll
        for (int jj = 0; jj < 2; ++jj) {
            const size_t off =
                (((size_t)(w * 2 + jj) * I_ + i0 + i) * D_ + lb) * F_;
            const float4* sw = reinterpret_cast<const float4*>(Wf + off);
            f16x8 af = cvt8(sw[0], sw[1]);
            if (bg == 0) *reinterpret_cast<f16x8*>(Wt + off) = af;
            sacc[jj][0] = __builtin_amdgcn_mfma_f32_16x16x32_f16(
                af, xv0, sacc[jj][0], 0, 0, 0);
            sacc[jj][1] = __builtin_amdgcn_mfma_f32_16x16x32_f16(
                af, xv1, sacc[jj][1], 0, 0, 0);
        }
    }

    #pragma unroll
    for (int jj = 0; jj < 2; ++jj) {
        const int j = w * 2 + jj;
        #pragma unroll
        for (int bh = 0; bh < 2; ++bh) {
            f32x4 sv = sacc[jj][bh] * 0.0625f;
            #pragma unroll
            for (int r = 0; r < 4; ++r)
                slds[(bh * 16 + lb) * SROW + j * D_ + lq * 4 + r] = sv[r];
        }
    }
    __syncthreads();
    {
        const int b = t >> 4, seg = t & 15;
        float o[16];
        #pragma unroll
        for (int k = 0; k < 16; ++k)
            o[k] = slds[b * SROW + seg * 16 + k];
        f16x8 o0 = {(f16)o[0], (f16)o[1], (f16)o[2],  (f16)o[3],
                    (f16)o[4], (f16)o[5], (f16)o[6],  (f16)o[7]};
        f16x8 o1 = {(f16)o[8], (f16)o[9], (f16)o[10], (f16)o[11],
                    (f16)o[12], (f16)o[13], (f16)o[14], (f16)o[15]};
        f16* dst = sp + ((size_t)it * B_ + b0 + b) * JD + seg * 16;
        *reinterpret_cast<f16x8*>(dst) = o0;
        *reinterpret_cast<f16x8*>(dst + 8) = o1;
    }
}

// ---------------------------------------------------------------------------
// Pass 1/2 — VERBATIM round 13/14/16 (proven 69 us config). BT2=32, 512 thr.
// NOTE (r15): no conditional register capture of af (cndmask trap, 69->85).
// NOTE (r17): BT=64 regresses via LDS->1 block/CU occupancy cliff (69->82).
// ---------------------------------------------------------------------------
__global__ __launch_bounds__(512, 4) void caps_pass1(
    const f16* __restrict__ Wt,     // [J][I][D][F]
    const f16* __restrict__ xt,     // [B][I][F]
    const float* __restrict__ vsum, // [B][JD]
    f16* __restrict__ sp)           // [NIT][B][JD]
{
    const int it = blockIdx.x, bg = blockIdx.y;
    const int i0 = it * IT, b0 = bg * BT2;
    const int t = threadIdx.x;
    const int w = t >> 6, l = t & 63;        // w in 0..7 -> j = w*2 + jj
    const int lb = l & 15, lq = l >> 4;

    __shared__ f16 xlds[IT][BT2][F_];       // 8 KB
    __shared__ union {
        float cl[J_ * IT * CLS];            // 33.8 KB softmax coeffs
        float slds[BT2 * SROW];             // 32.9 KB epilogue transpose
    } sh;

    // stage x~ tile: 512 threads, thread (b = t>>4, i = t&15)
    {
        const int b = t >> 4, i = t & 15;
        f16x8 v = *reinterpret_cast<const f16x8*>(
            xt + ((size_t)(b0 + b) * I_ + i0 + i) * F_);
        *reinterpret_cast<f16x8*>(&xlds[i][b][0]) = v;
    }

    // per-j W~ base pointers
    const f16* wp[2];
    #pragma unroll
    for (int jj = 0; jj < 2; ++jj)
        wp[jj] = Wt + (((size_t)(w * 2 + jj) * I_ + i0) * D_ + lb) * F_;

    const f32x4 zero = {0.f, 0.f, 0.f, 0.f};

    // v fragments: vr[jj][bh] = vsum[b0+bh*16+lb][j][lq*4 .. +3]
    float4 vr[2][2];
    #pragma unroll
    for (int jj = 0; jj < 2; ++jj)
        #pragma unroll
        for (int bh = 0; bh < 2; ++bh)
            vr[jj][bh] = *reinterpret_cast<const float4*>(
                vsum + (size_t)(b0 + bh * 16 + lb) * JD +
                (w * 2 + jj) * D_ + lq * 4);
    __syncthreads();

    // ---- Phase A: logits (af loaded once per (il,jj), reused for both bh) --
    #pragma unroll 4
    for (int il = 0; il < IT; ++il) {
        f16x8 bf0 = {0, 0, 0, 0, 0, 0, 0, 0};
        f16x8 bf1 = {0, 0, 0, 0, 0, 0, 0, 0};
        if (l < 16) {
            bf0 = *reinterpret_cast<const f16x8*>(&xlds[il][lb][0]);
            bf1 = *reinterpret_cast<const f16x8*>(&xlds[il][16 + lb][0]);
        }
        #pragma unroll
        for (int jj = 0; jj < 2; ++jj) {
            f16x8 af = *reinterpret_cast<const f16x8*>(wp[jj] + il * (D_ * F_));
            f32x4 u0 = __builtin_amdgcn_mfma_f32_16x16x32_f16(af, bf0, zero, 0, 0, 0);
            float p0 = u0[0] * vr[jj][0].x + u0[1] * vr[jj][0].y +
                       u0[2] * vr[jj][0].z + u0[3] * vr[jj][0].w;
            p0 = fold32(fold16(p0));
            f32x4 u1 = __builtin_amdgcn_mfma_f32_16x16x32_f16(af, bf1, zero, 0, 0, 0);
            float p1 = u1[0] * vr[jj][1].x + u1[1] * vr[jj][1].y +
                       u1[2] * vr[jj][1].z + u1[3] * vr[jj][1].w;
            p1 = fold32(fold16(p1));
            if (l < 16) {
                const int j = w * 2 + jj;
                sh.cl[(j * IT + il) * CLS + lb] = p0;
                sh.cl[(j * IT + il) * CLS + 16 + lb] = p1;
            }
        }
    }
    __syncthreads();

    // ---- softmax over j: thread (i = t>>5, b = t&31) ----
    {
        const int i = t >> 5, b = t & 31;
        float e[J_];
        float mx = -1e30f;
        #pragma unroll
        for (int j = 0; j < J_; ++j) {
            e[j] = sh.cl[(j * IT + i) * CLS + b];
            mx = fmaxf(mx, e[j]);
        }
        float ssum = 0.f;
        #pragma unroll
        for (int j = 0; j < J_; ++j) { e[j] = __expf(e[j] - mx); ssum += e[j]; }
        const float inv = 1.f / ssum;
        #pragma unroll
        for (int j = 0; j < J_; ++j) sh.cl[(j * IT + i) * CLS + b] = e[j] * inv;
    }
    __syncthreads();

    // ---- Phase C: s-GEMM, K=(i16,f8)=128 -> 4 MFMAs per (j,bh) ----
    f32x4 sacc[2][2] = {{zero, zero}, {zero, zero}};
    #pragma unroll
    for (int m = 0; m < 4; ++m) {
        const int i = m * 4 + lq;
        f16x8 xv0 = *reinterpret_cast<const f16x8*>(&xlds[i][lb][0]);
        f16x8 xv1 = *reinterpret_cast<const f16x8*>(&xlds[i][16 + lb][0]);
        #pragma unroll
        for (int jj = 0; jj < 2; ++jj) {
            const int j = w * 2 + jj;
            f16x8 af = *reinterpret_cast<const f16x8*>(wp[jj] + i * (D_ * F_));
            const f16 c0 = (f16)sh.cl[(j * IT + i) * CLS + lb];
            const f16 c1 = (f16)sh.cl[(j * IT + i) * CLS + 16 + lb];
            f16x8 bf0 = xv0 * c0;          // v_pk_mul_f16
            f16x8 bf1 = xv1 * c1;
            sacc[jj][0] = __builtin_amdgcn_mfma_f32_16x16x32_f16(
                af, bf0, sacc[jj][0], 0, 0, 0);
            sacc[jj][1] = __builtin_amdgcn_mfma_f32_16x16x32_f16(
                af, bf1, sacc[jj][1], 0, 0, 0);
        }
    }
    __syncthreads();   // slds aliases cl: phase-C cl reads must finish

    // ---- epilogue: LDS transpose -> coalesced f16 store ----
    #pragma unroll
    for (int jj = 0; jj < 2; ++jj) {
        const int j = w * 2 + jj;
        #pragma unroll
        for (int bh = 0; bh < 2; ++bh)
            #pragma unroll
            for (int r = 0; r < 4; ++r)
                sh.slds[(bh * 16 + lb) * SROW + j * D_ + lq * 4 + r] =
                    sacc[jj][bh][r];
    }
    __syncthreads();
    {
        const int b = t >> 4, seg = t & 15;   // 32 b x 16 segments
        float o[16];
        #pragma unroll
        for (int k = 0; k < 16; ++k)
            o[k] = sh.slds[b * SROW + seg * 16 + k];
        f16x8 o0 = {(f16)o[0], (f16)o[1], (f16)o[2],  (f16)o[3],
                    (f16)o[4], (f16)o[5], (f16)o[6],  (f16)o[7]};
        f16x8 o1 = {(f16)o[8], (f16)o[9], (f16)o[10], (f16)o[11],
                    (f16)o[12], (f16)o[13], (f16)o[14], (f16)o[15]};
        f16* dst = sp + ((size_t)it * B_ + b0 + b) * JD + seg * 16;
        *reinterpret_cast<f16x8*>(dst) = o0;
        *reinterpret_cast<f16x8*>(dst + 8) = o1;
    }
}

// ---------------------------------------------------------------------------
// Reduce over i-tiles + squash (verbatim rounds 7-16). Grid (B, 2), 512 thr.
// MODE 0: vA = squash(s); MODE 1: vB = vA + squash(s); MODE 2: out = squash(s)
// ---------------------------------------------------------------------------
template <int MODE>
__global__ __launch_bounds__(512) void caps_reduce(
    const f16* __restrict__ sp,    // [NIT][B][JD] f16
    const float* __restrict__ vA,  // [B][JD] (MODE==1)
    float* __restrict__ vout)      // [B][JD]
{
    const int b = blockIdx.x, jh = blockIdx.y;
    const int t = threadIdx.x;
    const int g = t >> 4, c8 = t & 15;
    constexpr int ITS = NIT / 32;  // 4

    float acc[8] = {0.f, 0.f, 0.f, 0.f, 0.f, 0.f, 0.f, 0.f};
    const f16* base = sp + ((size_t)(g * ITS) * B_ + b) * JD + jh * 128 + c8 * 8;
    #pragma unroll
    for (int k = 0; k < ITS; ++k) {
        f16x8 v = *reinterpret_cast<const f16x8*>(base + (size_t)k * B_ * JD);
        #pragma unroll
        for (int e = 0; e < 8; ++e) acc[e] += (float)v[e];
    }

    __shared__ float lds[32][128];
    #pragma unroll
    for (int e = 0; e < 8; ++e) lds[g][c8 * 8 + e] = acc[e];
    __syncthreads();

    if (t < 128) {
        float a = 0.f;
        #pragma unroll
        for (int gg = 0; gg < 32; ++gg) a += lds[gg][t];
        const float sq = row_sum16(a * a);
        const float scale = sq / (1.f + sq) * rsqrtf(sq + 1e-7f);
        float v = scale * a;
        const int jd = jh * 128 + t;
        if (MODE == 1) v += vA[(size_t)b * JD + jd];
        vout[(size_t)b * JD + jd] = v;
    }
}

extern "C" void kernel_launch(void* const* d_in, const int* in_sizes, int n_in,
                              void* d_out, int out_size, void* d_ws,
                              size_t ws_size, hipStream_t stream) {
    const float* x = (const float*)d_in[0];   // [128, 2048, 8]
    const float* W = (const float*)d_in[1];   // [16, 2048, 16, 8]
    float* out = (float*)d_out;               // [128, 16, 16]

    const size_t NW = (size_t)J_ * I_ * D_ * F_;   // 4,194,304
    const size_t NX = (size_t)B_ * I_ * F_;        // 2,097,152
    const size_t NSP = (size_t)NIT * B_ * JD;      // 4,194,304

    f16* Wt = (f16*)d_ws;
    f16* xt = Wt + NW;
    f16* sp = xt + NX;
    float* vA = (float*)(sp + NSP);
    float* vB = vA + (size_t)B_ * JD;

    dim3 grid(NIT, NBG2), blk(512);
    dim3 rgrid(B_, 2), rblk(512);

    // r=0 (+ fused cvt): uniform c -> sp -> vA = v0
    caps_pass0<<<grid, blk, 0, stream>>>(W, x, Wt, xt, sp);
    caps_reduce<0><<<rgrid, rblk, 0, stream>>>(sp, nullptr, vA);
    // r=1: logits = vA.u_hat -> sp -> vB = vA + v1
    caps_pass1<<<grid, blk, 0, stream>>>(Wt, xt, vA, sp);
    caps_reduce<1><<<rgrid, rblk, 0, stream>>>(sp, vA, vB);
    // r=2: logits = vB.u_hat -> sp -> out
    caps_pass1<<<grid, blk, 0, stream>>>(Wt, xt, vB, sp);
    caps_reduce<2><<<rgrid, rblk, 0, stream>>>(sp, nullptr, out);
}